// Round 5
// baseline (432.488 us; speedup 1.0000x reference)
//
#include <hip/hip_runtime.h>

// Problem constants (from reference setup_inputs)
#define BATCH 16
#define CIN   3
#define H     384
#define W     384
#define HO    382
#define WO    382
#define OFFC  18    // offset channels = 2*K
#define OOUT  3     // dcn output channels
#define KTAPS 9

// Tiling: 32x8 output pixels per 256-thread block, x staged in LDS with halo.
#define TX    32
#define TY    8
#define TM    4                   // halo margin for offsets (|off|<=3 guaranteed fast path)
#define ROWS  (TY + 2 + 2 * TM)   // 18
#define COLS  (TX + 2 + 2 * TM)   // 42
#define LSTR  43                  // padded LDS row stride (odd -> conflict-free)
#define NTX   12                  // ceil(382/32)
#define NTY   48                  // ceil(382/8)

__global__ __launch_bounds__(256)
void deform_tile_kernel(const float* __restrict__ x,
                        const float* __restrict__ conv_w,
                        const float* __restrict__ conv_b,
                        const float* __restrict__ dcn_w,
                        const float* __restrict__ dcn_b,
                        float* __restrict__ out)
{
    __shared__ float s_x[CIN * ROWS * LSTR];   // 2322 floats = 9.3 KB
    __shared__ float s_cw[OFFC * 27];
    __shared__ float s_cb[OFFC];
    __shared__ float s_dw[OOUT * 27];
    __shared__ float s_db[OOUT];

    const int t = threadIdx.x;

    // Decode tile
    const int bid = blockIdx.x;
    const int b   = bid / (NTY * NTX);
    const int rem = bid - b * (NTY * NTX);
    const int tyb = rem / NTX;
    const int txb = rem - tyb * NTX;
    const int ho0 = tyb * TY;
    const int wo0 = txb * TX;
    const int gy0 = ho0 - TM;    // staged-region origin (may be <0)
    const int gx0 = wo0 - TM;

    const float* xb = x + b * (CIN * H * W);

    // Stage weights (OFFC*27=486 > 256 -> strided)
    for (int i = t; i < OFFC * 27; i += 256) s_cw[i] = conv_w[i];
    if (t < OFFC)      s_cb[t] = conv_b[t];
    if (t < OOUT * 27) s_dw[t] = dcn_w[t];
    if (t < OOUT)      s_db[t] = dcn_b[t];

    // Stage x tile + halo, edge-clamped (cell r holds x[clamp(gy0+r)] so any
    // clamped sample coord maps to a valid cell when in index range).
    for (int i = t; i < CIN * ROWS * COLS; i += 256) {
        const int c  = i / (ROWS * COLS);
        const int r2 = i - c * (ROWS * COLS);
        const int r  = r2 / COLS;
        const int cc = r2 - r * COLS;
        const int gy = min(max(gy0 + r, 0), H - 1);
        const int gx = min(max(gx0 + cc, 0), W - 1);
        s_x[c * (ROWS * LSTR) + r * LSTR + cc] = xb[c * (H * W) + gy * W + gx];
    }
    __syncthreads();

    const int ty = t >> 5;          // 0..7
    const int tx = t & 31;          // 0..31
    const int ho = ho0 + ty;
    const int wo = wo0 + tx;
    if (ho >= HO || wo >= WO) return;

    const int lr = ty + TM;         // patch row in LDS
    const int lc = tx + TM;         // patch col in LDS

    // Patch for the offset conv, from LDS.
    float xp[CIN][3][3];
    #pragma unroll
    for (int c = 0; c < CIN; ++c)
        #pragma unroll
        for (int i = 0; i < 3; ++i)
            #pragma unroll
            for (int j = 0; j < 3; ++j)
                xp[c][i][j] = s_x[c * (ROWS * LSTR) + (lr + i) * LSTR + (lc + j)];

    // Offset conv: 18 channels.
    float off[OFFC];
    #pragma unroll
    for (int o = 0; o < OFFC; ++o) {
        float a = s_cb[o];
        const float* wv = &s_cw[o * 27];
        #pragma unroll
        for (int c = 0; c < CIN; ++c)
            #pragma unroll
            for (int i = 0; i < 3; ++i)
                #pragma unroll
                for (int j = 0; j < 3; ++j)
                    a = fmaf(wv[c * 9 + i * 3 + j], xp[c][i][j], a);
        off[o] = a;
    }

    float a0 = s_db[0], a1 = s_db[1], a2 = s_db[2];

    #pragma unroll
    for (int k = 0; k < KTAPS; ++k) {
        const int ky = k / 3;
        const int kx = k % 3;
        const float py = off[2 * k]     + (float)(ho + ky);
        const float px = off[2 * k + 1] + (float)(wo + kx);
        const float y0f = floorf(py);
        const float x0f = floorf(px);
        const float wy = py - y0f;
        const float wx = px - x0f;
        const int y0 = (int)y0f;
        const int x0 = (int)x0f;
        const int y1 = y0 + 1;
        const int x1 = x0 + 1;

        const bool vy0 = (y0 >= 0) && (y0 < H);
        const bool vy1 = (y1 >= 0) && (y1 < H);
        const bool vx0 = (x0 >= 0) && (x0 < W);
        const bool vx1 = (x1 >= 0) && (x1 < W);

        const int cy0 = min(max(y0, 0), H - 1);
        const int cy1 = min(max(y1, 0), H - 1);
        const int cx0 = min(max(x0, 0), W - 1);
        const int cx1 = min(max(x1, 0), W - 1);

        const float w00 = (vy0 && vx0) ? (1.f - wy) * (1.f - wx) : 0.f;
        const float w01 = (vy0 && vx1) ? (1.f - wy) * wx         : 0.f;
        const float w10 = (vy1 && vx0) ? wy * (1.f - wx)         : 0.f;
        const float w11 = (vy1 && vx1) ? wy * wx                 : 0.f;

        // LDS-region coordinates (clamped coords always map to valid cells
        // when the index is in range).
        const int r0 = cy0 - gy0;
        const int r1 = cy1 - gy0;
        const int c0 = cx0 - gx0;
        const int c1 = cx1 - gx0;
        const bool inlds = ((unsigned)r0 < ROWS) && ((unsigned)r1 < ROWS) &&
                           ((unsigned)c0 < COLS) && ((unsigned)c1 < COLS);

        float s00_0, s01_0, s10_0, s11_0;
        float s00_1, s01_1, s10_1, s11_1;
        float s00_2, s01_2, s10_2, s11_2;
        if (__builtin_expect(inlds, 1)) {
            const int i00 = r0 * LSTR + c0;
            const int i01 = r0 * LSTR + c1;
            const int i10 = r1 * LSTR + c0;
            const int i11 = r1 * LSTR + c1;
            s00_0 = s_x[i00]; s01_0 = s_x[i01]; s10_0 = s_x[i10]; s11_0 = s_x[i11];
            s00_1 = s_x[ROWS * LSTR + i00]; s01_1 = s_x[ROWS * LSTR + i01];
            s10_1 = s_x[ROWS * LSTR + i10]; s11_1 = s_x[ROWS * LSTR + i11];
            s00_2 = s_x[2 * ROWS * LSTR + i00]; s01_2 = s_x[2 * ROWS * LSTR + i01];
            s10_2 = s_x[2 * ROWS * LSTR + i10]; s11_2 = s_x[2 * ROWS * LSTR + i11];
        } else {
            const int i00 = cy0 * W + cx0;
            const int i01 = cy0 * W + cx1;
            const int i10 = cy1 * W + cx0;
            const int i11 = cy1 * W + cx1;
            s00_0 = xb[i00]; s01_0 = xb[i01]; s10_0 = xb[i10]; s11_0 = xb[i11];
            s00_1 = xb[H * W + i00]; s01_1 = xb[H * W + i01];
            s10_1 = xb[H * W + i10]; s11_1 = xb[H * W + i11];
            s00_2 = xb[2 * H * W + i00]; s01_2 = xb[2 * H * W + i01];
            s10_2 = xb[2 * H * W + i10]; s11_2 = xb[2 * H * W + i11];
        }

        float s0 = s00_0 * w00; s0 = fmaf(s01_0, w01, s0); s0 = fmaf(s10_0, w10, s0); s0 = fmaf(s11_0, w11, s0);
        float s1 = s00_1 * w00; s1 = fmaf(s01_1, w01, s1); s1 = fmaf(s10_1, w10, s1); s1 = fmaf(s11_1, w11, s1);
        float s2 = s00_2 * w00; s2 = fmaf(s01_2, w01, s2); s2 = fmaf(s10_2, w10, s2); s2 = fmaf(s11_2, w11, s2);

        a0 = fmaf(s_dw[0 * 27 + 0 * 9 + k], s0, a0);
        a0 = fmaf(s_dw[0 * 27 + 1 * 9 + k], s1, a0);
        a0 = fmaf(s_dw[0 * 27 + 2 * 9 + k], s2, a0);
        a1 = fmaf(s_dw[1 * 27 + 0 * 9 + k], s0, a1);
        a1 = fmaf(s_dw[1 * 27 + 1 * 9 + k], s1, a1);
        a1 = fmaf(s_dw[1 * 27 + 2 * 9 + k], s2, a1);
        a2 = fmaf(s_dw[2 * 27 + 0 * 9 + k], s0, a2);
        a2 = fmaf(s_dw[2 * 27 + 1 * 9 + k], s1, a2);
        a2 = fmaf(s_dw[2 * 27 + 2 * 9 + k], s2, a2);
    }

    const int obase = b * (OOUT * HO * WO) + ho * WO + wo;
    __builtin_nontemporal_store(a0, out + obase);
    __builtin_nontemporal_store(a1, out + obase + HO * WO);
    __builtin_nontemporal_store(a2, out + obase + 2 * HO * WO);
}

extern "C" void kernel_launch(void* const* d_in, const int* in_sizes, int n_in,
                              void* d_out, int out_size, void* d_ws, size_t ws_size,
                              hipStream_t stream) {
    const float* x      = (const float*)d_in[0];
    const float* conv_w = (const float*)d_in[1];
    const float* conv_b = (const float*)d_in[2];
    const float* dcn_w  = (const float*)d_in[3];
    const float* dcn_b  = (const float*)d_in[4];
    float* out = (float*)d_out;

    const int blocks = BATCH * NTY * NTX;   // 16*48*12 = 9216
    deform_tile_kernel<<<blocks, 256, 0, stream>>>(x, conv_w, conv_b, dcn_w, dcn_b, out);
}